// Round 2
// baseline (31887.109 us; speedup 1.0000x reference)
//
#include <hip/hip_runtime.h>

#define NSEQ   4096
#define TSTEPS 512
#define FIN    5
#define HID    64
#define SPB    8      // sequences per block
#define TCHUNK 64     // x-staging chunk (steps)
#define BLK    512    // threads per block (8 waves)

__device__ __forceinline__ float fast_sigmoid(float x) {
    return __builtin_amdgcn_rcpf(1.0f + __expf(-x));
}
__device__ __forceinline__ float fast_tanh(float x) {
    // tanh(x) = 1 - 2/(e^{2x}+1); correct limits at +/-inf via exp overflow/underflow
    return 1.0f - 2.0f * __builtin_amdgcn_rcpf(1.0f + __expf(2.0f * x));
}

// Block: 512 threads. Gate phase: thread = (gate row g = tid>>1, K-half = tid&1).
// Each thread holds 32 Whh weights in 8 NAMED float4s (guaranteed VGPRs — a
// 64-float private array went to scratch in R1 and cost 90 GB of HBM traffic).
// Halves combine via __shfl_xor(.,1). Update phase: thread = (s=tid>>6, u=tid&63).
__global__ __launch_bounds__(BLK, 4)
void lstm_kernel(const float* __restrict__ feat,
                 const float* __restrict__ Wih,
                 const float* __restrict__ Whh,
                 const float* __restrict__ bih,
                 const float* __restrict__ bhh,
                 float* __restrict__ h_out) {
    __shared__ float h_lds[SPB][HID];          // current hidden state
    __shared__ float gates_lds[4][SPB][HID];   // activated gates
    __shared__ float x_lds[SPB * TCHUNK * FIN];

    const int tid  = threadIdx.x;
    const int g    = tid >> 1;    // gate row 0..255
    const int half = tid & 1;     // which 32-wide K-half
    const int k    = g >> 6;      // gate class (wave-uniform: 64 consecutive tids -> 32 g's)
    const int u    = g & 63;      // unit within gate
    const int us   = tid >> 6;    // update-phase seq 0..7
    const int uu   = tid & 63;    // update-phase unit
    const int seq0 = blockIdx.x * SPB;

    // Whh half-row -> 8 named float4 registers. Base = 64*g + 32*half = 32*tid.
    const float4* wp = reinterpret_cast<const float4*>(Whh + 32 * tid);
    const float4 w0 = wp[0], w1 = wp[1], w2 = wp[2], w3 = wp[3];
    const float4 w4 = wp[4], w5 = wp[5], w6 = wp[6], w7 = wp[7];
    const float* wih = Wih + FIN * g;
    const float wf0 = wih[0], wf1 = wih[1], wf2 = wih[2], wf3 = wih[3], wf4 = wih[4];
    const float br = bih[g] + bhh[g];

    h_lds[us][uu] = 0.0f;   // 512 threads cover all SPB*HID entries
    float c = 0.0f;
    __syncthreads();

    for (int t0 = 0; t0 < TSTEPS; t0 += TCHUNK) {
        // stage x chunk (coalesced); prior step's end barrier protects x_lds
#pragma unroll
        for (int it = 0; it < (SPB * TCHUNK * FIN) / BLK; ++it) {
            int idx = tid + it * BLK;
            int s   = idx / (TCHUNK * FIN);
            int off = idx - s * (TCHUNK * FIN);
            x_lds[idx] = feat[((size_t)(seq0 + s) * TSTEPS + t0) * FIN + off];
        }
        __syncthreads();

        for (int tt = 0; tt < TCHUNK; ++tt) {
            // ---- gate phase: half-dot of Whh row with h[s] ----
            float acc[SPB];
            if (half == 0) {
#pragma unroll
                for (int s = 0; s < SPB; ++s) {
                    const float* xp = &x_lds[(s * TCHUNK + tt) * FIN];  // broadcast reads
                    acc[s] = br + wf0 * xp[0] + wf1 * xp[1] + wf2 * xp[2]
                                + wf3 * xp[3] + wf4 * xp[4];
                }
            } else {
#pragma unroll
                for (int s = 0; s < SPB; ++s) acc[s] = 0.0f;
            }
#pragma unroll
            for (int j4 = 0; j4 < 8; ++j4) {
#pragma unroll
                for (int s = 0; s < SPB; ++s) {
                    float4 h4 = *reinterpret_cast<const float4*>(&h_lds[s][32 * half + 4 * j4]);
                    float4 w  = (j4 == 0) ? w0 : (j4 == 1) ? w1 : (j4 == 2) ? w2 :
                                (j4 == 3) ? w3 : (j4 == 4) ? w4 : (j4 == 5) ? w5 :
                                (j4 == 6) ? w6 : w7;
                    acc[s] += w.x * h4.x + w.y * h4.y + w.z * h4.z + w.w * h4.w;
                }
            }
            // pair-sum across halves (adjacent lanes), activate on even lane
#pragma unroll
            for (int s = 0; s < SPB; ++s) {
                float tot = acc[s] + __shfl_xor(acc[s], 1);
                if (half == 0) {
                    float act = (k == 2) ? fast_tanh(tot) : fast_sigmoid(tot);
                    gates_lds[k][s][u] = act;
                }
            }
            __syncthreads();

            // ---- update phase: c,h for (us, uu) ----
            float gi = gates_lds[0][us][uu];
            float gf = gates_lds[1][us][uu];
            float gg = gates_lds[2][us][uu];
            float go = gates_lds[3][us][uu];
            c = gf * c + gi * gg;
            float h = go * fast_tanh(c);
            h_lds[us][uu] = h;
            __syncthreads();
        }
    }
    h_out[(size_t)(seq0 + us) * HID + uu] = h_lds[us][uu];
}

// pred = leaky_relu(h_last @ Wd^T + bd); also zero the ws accumulators
__global__ void pred_kernel(const float* __restrict__ h_in,
                            const float* __restrict__ Wd,
                            const float* __restrict__ bd,
                            float* __restrict__ pred_out,
                            float* __restrict__ accums) {
    int n = blockIdx.x * blockDim.x + threadIdx.x;
    if (blockIdx.x == 0 && threadIdx.x < 4) accums[threadIdx.x] = 0.0f;
    const float* h = &h_in[(size_t)n * HID];
    float s = bd[0];
#pragma unroll
    for (int j4 = 0; j4 < HID / 4; ++j4) {
        float4 h4 = *reinterpret_cast<const float4*>(&h[j4 * 4]);
        s += Wd[j4 * 4 + 0] * h4.x + Wd[j4 * 4 + 1] * h4.y +
             Wd[j4 * 4 + 2] * h4.z + Wd[j4 * 4 + 3] * h4.w;
    }
    float p = (s >= 0.0f) ? s : 0.2f * s;
    pred_out[n] = p;
}

__global__ void regloss_kernel(const float* __restrict__ pred,
                               const float* __restrict__ ret,
                               const int* __restrict__ mask,
                               float* __restrict__ accums) {
    int n = blockIdx.x * blockDim.x + threadIdx.x;
    float m = (mask[n] != 0) ? 1.0f : 0.0f;
    float d = pred[n] - ret[n];
    float v = d * d * m;
#pragma unroll
    for (int off = 32; off > 0; off >>= 1) {
        v += __shfl_down(v, off, 64);
        m += __shfl_down(m, off, 64);
    }
    if ((threadIdx.x & 63) == 0) {
        atomicAdd(&accums[0], v);
        atomicAdd(&accums[1], m);
    }
}

// rank loss: 256 blocks x 16 i's each, 16-way j split per i; data staged in LDS
__global__ __launch_bounds__(256)
void rankloss_kernel(const float* __restrict__ pred,
                     const float* __restrict__ ret,
                     const int* __restrict__ mask,
                     float* __restrict__ accums) {
    __shared__ float sp[NSEQ];
    __shared__ float sg[NSEQ];
    __shared__ float sq[NSEQ];
    int tid = threadIdx.x;
    for (int idx = tid; idx < NSEQ; idx += 256) {
        sp[idx] = pred[idx];
        sg[idx] = ret[idx];
        sq[idx] = (mask[idx] != 0) ? 1.0f : 0.0f;
    }
    __syncthreads();

    int iloc = tid >> 4;       // 0..15
    int jp   = tid & 15;
    int i    = blockIdx.x * 16 + iloc;
    float pi = sp[i], gi = sg[i], qi = sq[i];
    float sum = 0.0f;
    for (int j = jp; j < NSEQ; j += 16) {
        float t = -(sp[j] - pi) * (sg[j] - gi);
        sum += fmaxf(t, 0.0f) * sq[j];
    }
    sum *= qi;
#pragma unroll
    for (int off = 32; off > 0; off >>= 1) sum += __shfl_down(sum, off, 64);
    __shared__ float wsum[4];
    if ((tid & 63) == 0) wsum[tid >> 6] = sum;
    __syncthreads();
    if (tid == 0) atomicAdd(&accums[2], wsum[0] + wsum[1] + wsum[2] + wsum[3]);
}

__global__ void final_kernel(const float* __restrict__ accums,
                             float* __restrict__ out) {
    float reg  = accums[0] / (accums[1] + 1e-8f);
    float rank = accums[2] / 16777216.0f;   // N*N
    out[NSEQ + 0] = reg + rank;
    out[NSEQ + 1] = reg;
    out[NSEQ + 2] = rank;
}

extern "C" void kernel_launch(void* const* d_in, const int* in_sizes, int n_in,
                              void* d_out, int out_size, void* d_ws, size_t ws_size,
                              hipStream_t stream) {
    const float* feat = (const float*)d_in[0];
    const float* ret  = (const float*)d_in[1];
    const int*   mask = (const int*)d_in[2];
    const float* Wih  = (const float*)d_in[3];
    const float* Whh  = (const float*)d_in[4];
    const float* bih  = (const float*)d_in[5];
    const float* bhh  = (const float*)d_in[6];
    const float* Wd   = (const float*)d_in[7];
    const float* bd   = (const float*)d_in[8];
    float* out    = (float*)d_out;
    float* accums = (float*)d_ws;            // [0..3] loss partials
    float* h_out  = (float*)d_ws + 16;       // [NSEQ][HID]

    lstm_kernel<<<NSEQ / SPB, BLK, 0, stream>>>(feat, Wih, Whh, bih, bhh, h_out);
    pred_kernel<<<NSEQ / 256, 256, 0, stream>>>(h_out, Wd, bd, out, accums);
    regloss_kernel<<<NSEQ / 256, 256, 0, stream>>>(out, ret, mask, accums);
    rankloss_kernel<<<256, 256, 0, stream>>>(out, ret, mask, accums);
    final_kernel<<<1, 1, 0, stream>>>(accums, out);
}

// Round 3
// 1743.355 us; speedup vs baseline: 18.2907x; 18.2907x over previous
//
#include <hip/hip_runtime.h>

#define NSEQ   4096
#define TSTEPS 512
#define FIN    5
#define HID    64
#define SPB    4      // sequences per block
#define TCHUNK 64     // x-staging chunk (steps)
#define BLK    256

__device__ __forceinline__ float fast_sigmoid(float x) {
    return __builtin_amdgcn_rcpf(1.0f + __expf(-x));
}
__device__ __forceinline__ float fast_tanh(float x) {
    // tanh(x) = 1 - 2/(e^{2x}+1); correct limits at +/-inf via exp overflow/underflow
    return 1.0f - 2.0f * __builtin_amdgcn_rcpf(1.0f + __expf(2.0f * x));
}

// Block: 256 threads. Gate phase: thread = gate row g=tid (k=g>>6 gate class,
// wave-uniform; u=g&63). Whh row lives in 16 NAMED float4s (64 VGPRs) — R1's
// 64-float array went to scratch (promote-alloca gave up), R2's launch_bounds
// min-occupancy arg capped VGPRs at 64 and spilled. Plain launch_bounds(256)
// + named vars: allocator free up to 256 VGPRs, zero scratch.
// All LDS reads in the gate phase are same-address wave broadcasts (free).
// Update phase: thread = (s=tid>>6, u=tid&63).
__global__ __launch_bounds__(BLK)
void lstm_kernel(const float* __restrict__ feat,
                 const float* __restrict__ Wih,
                 const float* __restrict__ Whh,
                 const float* __restrict__ bih,
                 const float* __restrict__ bhh,
                 float* __restrict__ h_out) {
    __shared__ float h_lds[SPB][HID];          // current hidden state
    __shared__ float gates_lds[4][SPB][HID];   // activated gates
    __shared__ float x_lds[SPB * TCHUNK * FIN];

    const int tid  = threadIdx.x;
    const int g    = tid;         // gate row 0..255
    const int k    = tid >> 6;    // gate class (wave-uniform)
    const int u    = tid & 63;    // unit within gate
    const int us   = tid >> 6;    // update-phase sequence 0..3
    const int uu   = tid & 63;    // update-phase unit
    const int seq0 = blockIdx.x * SPB;

    // Whh row -> 16 named float4 registers (64 VGPRs, reused 512 steps)
    const float4* wp = reinterpret_cast<const float4*>(Whh + HID * g);
    const float4 w0 = wp[0],  w1 = wp[1],  w2 = wp[2],  w3 = wp[3];
    const float4 w4 = wp[4],  w5 = wp[5],  w6 = wp[6],  w7 = wp[7];
    const float4 w8 = wp[8],  w9 = wp[9],  wA = wp[10], wB = wp[11];
    const float4 wC = wp[12], wD = wp[13], wE = wp[14], wF = wp[15];
    const float* wih = Wih + FIN * g;
    const float wf0 = wih[0], wf1 = wih[1], wf2 = wih[2], wf3 = wih[3], wf4 = wih[4];
    const float br = bih[g] + bhh[g];

    h_lds[us][uu] = 0.0f;   // 256 threads cover all SPB*HID entries
    float c = 0.0f;
    __syncthreads();

    for (int t0 = 0; t0 < TSTEPS; t0 += TCHUNK) {
        // stage x chunk (coalesced); prior step's end barrier protects x_lds
#pragma unroll
        for (int it = 0; it < (SPB * TCHUNK * FIN) / BLK; ++it) {
            int idx = tid + it * BLK;
            int s   = idx / (TCHUNK * FIN);
            int off = idx - s * (TCHUNK * FIN);
            x_lds[idx] = feat[((size_t)(seq0 + s) * TSTEPS + t0) * FIN + off];
        }
        __syncthreads();

        for (int tt = 0; tt < TCHUNK; ++tt) {
            // ---- gate phase: acc[s] = b + Wih.x[s] + Whh_row . h[s] ----
            float acc0, acc1, acc2, acc3;
            {
                const float* x0 = &x_lds[(0 * TCHUNK + tt) * FIN];  // broadcast
                const float* x1 = &x_lds[(1 * TCHUNK + tt) * FIN];
                const float* x2 = &x_lds[(2 * TCHUNK + tt) * FIN];
                const float* x3 = &x_lds[(3 * TCHUNK + tt) * FIN];
                acc0 = br + wf0*x0[0] + wf1*x0[1] + wf2*x0[2] + wf3*x0[3] + wf4*x0[4];
                acc1 = br + wf0*x1[0] + wf1*x1[1] + wf2*x1[2] + wf3*x1[3] + wf4*x1[4];
                acc2 = br + wf0*x2[0] + wf1*x2[1] + wf2*x2[2] + wf3*x2[3] + wf4*x2[4];
                acc3 = br + wf0*x3[0] + wf1*x3[1] + wf2*x3[2] + wf3*x3[3] + wf4*x3[4];
            }
#define DOT4(J, W)                                                             \
            {                                                                  \
                float4 h40 = *reinterpret_cast<const float4*>(&h_lds[0][4*J]); \
                float4 h41 = *reinterpret_cast<const float4*>(&h_lds[1][4*J]); \
                float4 h42 = *reinterpret_cast<const float4*>(&h_lds[2][4*J]); \
                float4 h43 = *reinterpret_cast<const float4*>(&h_lds[3][4*J]); \
                acc0 += W.x*h40.x + W.y*h40.y + W.z*h40.z + W.w*h40.w;         \
                acc1 += W.x*h41.x + W.y*h41.y + W.z*h41.z + W.w*h41.w;         \
                acc2 += W.x*h42.x + W.y*h42.y + W.z*h42.z + W.w*h42.w;         \
                acc3 += W.x*h43.x + W.y*h43.y + W.z*h43.z + W.w*h43.w;         \
            }
            DOT4(0,  w0) DOT4(1,  w1) DOT4(2,  w2) DOT4(3,  w3)
            DOT4(4,  w4) DOT4(5,  w5) DOT4(6,  w6) DOT4(7,  w7)
            DOT4(8,  w8) DOT4(9,  w9) DOT4(10, wA) DOT4(11, wB)
            DOT4(12, wC) DOT4(13, wD) DOT4(14, wE) DOT4(15, wF)
#undef DOT4
            if (k == 2) {   // wave-uniform branch
                gates_lds[k][0][u] = fast_tanh(acc0);
                gates_lds[k][1][u] = fast_tanh(acc1);
                gates_lds[k][2][u] = fast_tanh(acc2);
                gates_lds[k][3][u] = fast_tanh(acc3);
            } else {
                gates_lds[k][0][u] = fast_sigmoid(acc0);
                gates_lds[k][1][u] = fast_sigmoid(acc1);
                gates_lds[k][2][u] = fast_sigmoid(acc2);
                gates_lds[k][3][u] = fast_sigmoid(acc3);
            }
            __syncthreads();

            // ---- update phase: c,h for (us, uu) ----
            float gi = gates_lds[0][us][uu];
            float gf = gates_lds[1][us][uu];
            float gg = gates_lds[2][us][uu];
            float go = gates_lds[3][us][uu];
            c = gf * c + gi * gg;
            float h = go * fast_tanh(c);
            h_lds[us][uu] = h;
            __syncthreads();
        }
    }
    h_out[(size_t)(seq0 + us) * HID + uu] = h_lds[us][uu];
}

// pred = leaky_relu(h_last @ Wd^T + bd); also zero the ws accumulators
__global__ void pred_kernel(const float* __restrict__ h_in,
                            const float* __restrict__ Wd,
                            const float* __restrict__ bd,
                            float* __restrict__ pred_out,
                            float* __restrict__ accums) {
    int n = blockIdx.x * blockDim.x + threadIdx.x;
    if (blockIdx.x == 0 && threadIdx.x < 4) accums[threadIdx.x] = 0.0f;
    const float* h = &h_in[(size_t)n * HID];
    float s = bd[0];
#pragma unroll
    for (int j4 = 0; j4 < HID / 4; ++j4) {
        float4 h4 = *reinterpret_cast<const float4*>(&h[j4 * 4]);
        s += Wd[j4 * 4 + 0] * h4.x + Wd[j4 * 4 + 1] * h4.y +
             Wd[j4 * 4 + 2] * h4.z + Wd[j4 * 4 + 3] * h4.w;
    }
    float p = (s >= 0.0f) ? s : 0.2f * s;
    pred_out[n] = p;
}

__global__ void regloss_kernel(const float* __restrict__ pred,
                               const float* __restrict__ ret,
                               const int* __restrict__ mask,
                               float* __restrict__ accums) {
    int n = blockIdx.x * blockDim.x + threadIdx.x;
    float m = (mask[n] != 0) ? 1.0f : 0.0f;
    float d = pred[n] - ret[n];
    float v = d * d * m;
#pragma unroll
    for (int off = 32; off > 0; off >>= 1) {
        v += __shfl_down(v, off, 64);
        m += __shfl_down(m, off, 64);
    }
    if ((threadIdx.x & 63) == 0) {
        atomicAdd(&accums[0], v);
        atomicAdd(&accums[1], m);
    }
}

// rank loss: 256 blocks x 16 i's each, 16-way j split per i; data staged in LDS
__global__ __launch_bounds__(256)
void rankloss_kernel(const float* __restrict__ pred,
                     const float* __restrict__ ret,
                     const int* __restrict__ mask,
                     float* __restrict__ accums) {
    __shared__ float sp[NSEQ];
    __shared__ float sg[NSEQ];
    __shared__ float sq[NSEQ];
    int tid = threadIdx.x;
    for (int idx = tid; idx < NSEQ; idx += 256) {
        sp[idx] = pred[idx];
        sg[idx] = ret[idx];
        sq[idx] = (mask[idx] != 0) ? 1.0f : 0.0f;
    }
    __syncthreads();

    int iloc = tid >> 4;       // 0..15
    int jp   = tid & 15;
    int i    = blockIdx.x * 16 + iloc;
    float pi = sp[i], gi = sg[i], qi = sq[i];
    float sum = 0.0f;
    for (int j = jp; j < NSEQ; j += 16) {
        float t = -(sp[j] - pi) * (sg[j] - gi);
        sum += fmaxf(t, 0.0f) * sq[j];
    }
    sum *= qi;
#pragma unroll
    for (int off = 32; off > 0; off >>= 1) sum += __shfl_down(sum, off, 64);
    __shared__ float wsum[4];
    if ((tid & 63) == 0) wsum[tid >> 6] = sum;
    __syncthreads();
    if (tid == 0) atomicAdd(&accums[2], wsum[0] + wsum[1] + wsum[2] + wsum[3]);
}

__global__ void final_kernel(const float* __restrict__ accums,
                             float* __restrict__ out) {
    float reg  = accums[0] / (accums[1] + 1e-8f);
    float rank = accums[2] / 16777216.0f;   // N*N
    out[NSEQ + 0] = reg + rank;
    out[NSEQ + 1] = reg;
    out[NSEQ + 2] = rank;
}

extern "C" void kernel_launch(void* const* d_in, const int* in_sizes, int n_in,
                              void* d_out, int out_size, void* d_ws, size_t ws_size,
                              hipStream_t stream) {
    const float* feat = (const float*)d_in[0];
    const float* ret  = (const float*)d_in[1];
    const int*   mask = (const int*)d_in[2];
    const float* Wih  = (const float*)d_in[3];
    const float* Whh  = (const float*)d_in[4];
    const float* bih  = (const float*)d_in[5];
    const float* bhh  = (const float*)d_in[6];
    const float* Wd   = (const float*)d_in[7];
    const float* bd   = (const float*)d_in[8];
    float* out    = (float*)d_out;
    float* accums = (float*)d_ws;            // [0..3] loss partials
    float* h_out  = (float*)d_ws + 16;       // [NSEQ][HID]

    lstm_kernel<<<NSEQ / SPB, BLK, 0, stream>>>(feat, Wih, Whh, bih, bhh, h_out);
    pred_kernel<<<NSEQ / 256, 256, 0, stream>>>(h_out, Wd, bd, out, accums);
    regloss_kernel<<<NSEQ / 256, 256, 0, stream>>>(out, ret, mask, accums);
    rankloss_kernel<<<256, 256, 0, stream>>>(out, ret, mask, accums);
    final_kernel<<<1, 1, 0, stream>>>(accums, out);
}

// Round 5
// 531.530 us; speedup vs baseline: 59.9912x; 3.2799x over previous
//
#include <hip/hip_runtime.h>

#define NSEQ   4096
#define TSTEPS 512
#define FIN    5
#define HID    64
#define SPB    16     // sequences per block (MFMA M)
#define BLK    256

// Neutral names — do NOT reuse HIP vector-type names like short8 (R4 crash suspect #1)
typedef __attribute__((ext_vector_type(8))) short bsh8;    // 8 bf16 in 4 VGPRs
typedef __attribute__((ext_vector_type(4))) float f32x4;   // MFMA accumulator

#define MFMA16(A, B, C) __builtin_amdgcn_mfma_f32_16x16x32_bf16((A), (B), (C), 0, 0, 0)

struct Frag2 { bsh8 hi; bsh8 lo; };

__device__ __forceinline__ unsigned short bf16hi_rn(float x) {
    unsigned u = __float_as_uint(x);
    return (unsigned short)((u + 0x7fffu + ((u >> 16) & 1u)) >> 16);
}
__device__ __forceinline__ void split_bf16(float v, unsigned short& h, unsigned short& l) {
    h = bf16hi_rn(v);
    float hf = __uint_as_float(((unsigned)h) << 16);
    l = bf16hi_rn(v - hf);
}

__device__ __forceinline__ float fast_sigmoid(float x) {
    return __builtin_amdgcn_rcpf(1.0f + __expf(-x));
}
__device__ __forceinline__ float fast_tanh(float x) {
    return 1.0f - 2.0f * __builtin_amdgcn_rcpf(1.0f + __expf(2.0f * x));
}

// B-fragment for 16x16x32 bf16: lane holds B[k = quad*8 + j][n = col] -> 8
// consecutive k elements of one W row (contiguous floats).
__device__ __forceinline__ Frag2 load_whh_frag(const float* __restrict__ Whh, int gate, int k) {
    const float* p = Whh + gate * HID + k;
    Frag2 r;
#pragma unroll
    for (int j = 0; j < 8; ++j) {
        unsigned short h, l;
        split_bf16(p[j], h, l);
        r.hi[j] = (short)h; r.lo[j] = (short)l;
    }
    return r;
}
// K-tile 2 = x-extension: k in [64,96). Only quad 0 (k 64..71) carries Wih cols 0..4.
__device__ __forceinline__ Frag2 load_wih_frag(const float* __restrict__ Wih, int gate, int quad) {
    Frag2 r;
#pragma unroll
    for (int j = 0; j < 8; ++j) { r.hi[j] = 0; r.lo[j] = 0; }
    if (quad == 0) {
#pragma unroll
        for (int j = 0; j < FIN; ++j) {
            unsigned short h, l;
            split_bf16(Wih[gate * FIN + j], h, l);
            r.hi[j] = (short)h; r.lo[j] = (short)l;
        }
    }
    return r;
}

// Split-bf16 MFMA LSTM. Block: 256 threads = 4 waves, 16 seqs.
// gates[16,256] = [h|x][16,96] @ [Whh|Wih]^T via mfma_f32_16x16x32_bf16
// (3 split passes: hi*hi + lo*hi + hi*lo). Wave w owns N-tiles {w,w+4,w+8,w+12}
// = all 4 gate classes of units [16w,16w+16): c stays in registers.
// h double-buffered in LDS as packed bf16 hi/lo vectors -> ONE barrier per step.
// LDS arrays are vector-typed (16B-aligned by construction; R4 cast 2B-aligned
// ushort arrays to vectors — crash suspect #2). Row pitch 9 vecs = 144 B -> A-row
// reads spread banks (2-way aliasing = free).
__global__ __launch_bounds__(BLK)
void lstm_kernel(const float* __restrict__ feat,
                 const float* __restrict__ Wih,
                 const float* __restrict__ Whh,
                 const float* __restrict__ bih,
                 const float* __restrict__ bhh,
                 float* __restrict__ h_out) {
    __shared__ bsh8 aA[2][2][SPB][9];   // [buf][0=hi,1=lo][seq][kvec 0..7; 8=pad] = 9216 B
    __shared__ bsh8 xA[2][64][SPB];     // [0=hi,1=lo][step-in-chunk][seq]       = 32768 B

    const int tid  = threadIdx.x;
    const int w    = tid >> 6;          // wave 0..3
    const int lane = tid & 63;
    const int col  = lane & 15;         // MFMA n (unit-in-group) / m (seq) index
    const int quad = lane >> 4;         // MFMA k-block
    const int u    = 16 * w + col;      // unit handled by this lane
    const int seq0 = blockIdx.x * SPB;

    // ---- persistent B fragments (96 VGPRs in named structs; R1/R2 spill lessons) ----
    const int g0 = 0 * HID + u, g1 = 1 * HID + u, g2 = 2 * HID + u, g3 = 3 * HID + u;
    Frag2 b00 = load_whh_frag(Whh, g0, quad * 8);
    Frag2 b01 = load_whh_frag(Whh, g0, 32 + quad * 8);
    Frag2 b02 = load_wih_frag(Wih, g0, quad);
    Frag2 b10 = load_whh_frag(Whh, g1, quad * 8);
    Frag2 b11 = load_whh_frag(Whh, g1, 32 + quad * 8);
    Frag2 b12 = load_wih_frag(Wih, g1, quad);
    Frag2 b20 = load_whh_frag(Whh, g2, quad * 8);
    Frag2 b21 = load_whh_frag(Whh, g2, 32 + quad * 8);
    Frag2 b22 = load_wih_frag(Wih, g2, quad);
    Frag2 b30 = load_whh_frag(Whh, g3, quad * 8);
    Frag2 b31 = load_whh_frag(Whh, g3, 32 + quad * 8);
    Frag2 b32 = load_wih_frag(Wih, g3, quad);

    const float bi  = bih[g0] + bhh[g0];
    const float bf_ = bih[g1] + bhh[g1];
    const float bg  = bih[g2] + bhh[g2];
    const float bo  = bih[g3] + bhh[g3];

    // zero h buffer 0 (aA[0] = first 2*16*9 = 288 contiguous vectors)
    {
        bsh8 z = {0, 0, 0, 0, 0, 0, 0, 0};
        bsh8* p = &aA[0][0][0][0];
        for (int idx = tid; idx < 2 * SPB * 9; idx += BLK) p[idx] = z;
    }

    float c_[4] = {0.f, 0.f, 0.f, 0.f};

    for (int c = 0; c < TSTEPS / 64; ++c) {
        const int t0 = c * 64;
        // ---- stage + split x for steps [t0, t0+64): one (t2,s) pair per item ----
#pragma unroll
        for (int it = 0; it < (64 * SPB) / BLK; ++it) {
            int idx = tid + it * BLK;
            int t2  = idx >> 4;
            int s   = idx & 15;
            const float* xp = feat + (size_t)(seq0 + s) * (TSTEPS * FIN) + (t0 + t2) * FIN;
            bsh8 vh = {0, 0, 0, 0, 0, 0, 0, 0};
            bsh8 vl = {0, 0, 0, 0, 0, 0, 0, 0};
#pragma unroll
            for (int j = 0; j < FIN; ++j) {
                unsigned short h, l;
                split_bf16(xp[j], h, l);
                vh[j] = (short)h; vl[j] = (short)l;
            }
            xA[0][t2][s] = vh;
            xA[1][t2][s] = vl;
        }
        __syncthreads();   // xA ready (also covers aA init at c=0; prior-chunk xA
                           // reads completed at the last step's end barrier)

        for (int tt = 0; tt < 64; ++tt) {
            const int t  = t0 + tt;
            const int b  = t & 1;
            const int nb = b ^ 1;

            // ---- A fragments: A[m=col][k=quad*8+j] ----
            const bsh8* ArH = &aA[b][0][col][0];
            const bsh8* ArL = &aA[b][1][col][0];
            bsh8 ah0 = ArH[quad];
            bsh8 ah1 = ArH[4 + quad];
            bsh8 al0 = ArL[quad];
            bsh8 al1 = ArL[4 + quad];
            bsh8 axh = xA[0][tt][col];   // same for all quads; B zero for k>=72
            bsh8 axl = xA[1][tt][col];

            // ---- 36 MFMAs: hi*hi + lo*hi + hi*lo (drop lo*lo) ----
            f32x4 acc0 = {0.f, 0.f, 0.f, 0.f};
            f32x4 acc1 = {0.f, 0.f, 0.f, 0.f};
            f32x4 acc2 = {0.f, 0.f, 0.f, 0.f};
            f32x4 acc3 = {0.f, 0.f, 0.f, 0.f};
#define QPASS(ACC, B0, B1, B2)                 \
            ACC = MFMA16(ah0, B0.hi, ACC);     \
            ACC = MFMA16(ah1, B1.hi, ACC);     \
            ACC = MFMA16(axh, B2.hi, ACC);     \
            ACC = MFMA16(al0, B0.hi, ACC);     \
            ACC = MFMA16(al1, B1.hi, ACC);     \
            ACC = MFMA16(axl, B2.hi, ACC);     \
            ACC = MFMA16(ah0, B0.lo, ACC);     \
            ACC = MFMA16(ah1, B1.lo, ACC);     \
            ACC = MFMA16(axh, B2.lo, ACC);
            QPASS(acc0, b00, b01, b02)
            QPASS(acc1, b10, b11, b12)
            QPASS(acc2, b20, b21, b22)
            QPASS(acc3, b30, b31, b32)
#undef QPASS

            // ---- epilogue: C/D layout col=lane&15 (unit), row=quad*4+r (seq) ----
#pragma unroll
            for (int r = 0; r < 4; ++r) {
                float gi = fast_sigmoid(acc0[r] + bi);
                float gf = fast_sigmoid(acc1[r] + bf_);
                float gg = fast_tanh  (acc2[r] + bg);
                float go = fast_sigmoid(acc3[r] + bo);
                c_[r] = gf * c_[r] + gi * gg;
                float hh = go * fast_tanh(c_[r]);
                unsigned short hb, lb;
                split_bf16(hh, hb, lb);
                int seqr = quad * 4 + r;
                ((unsigned short*)&aA[nb][0][seqr][0])[u] = hb;
                ((unsigned short*)&aA[nb][1][seqr][0])[u] = lb;
                if (t == TSTEPS - 1) {
                    h_out[(size_t)(seq0 + seqr) * HID + u] = hh;
                }
            }
            __syncthreads();   // aA[nb] (and xA reuse) visible before next step
        }
    }
}

// pred = leaky_relu(h_last @ Wd^T + bd); also zero the ws accumulators
__global__ void pred_kernel(const float* __restrict__ h_in,
                            const float* __restrict__ Wd,
                            const float* __restrict__ bd,
                            float* __restrict__ pred_out,
                            float* __restrict__ accums) {
    int n = blockIdx.x * blockDim.x + threadIdx.x;
    if (blockIdx.x == 0 && threadIdx.x < 4) accums[threadIdx.x] = 0.0f;
    const float* h = &h_in[(size_t)n * HID];
    float s = bd[0];
#pragma unroll
    for (int j4 = 0; j4 < HID / 4; ++j4) {
        float4 h4 = *reinterpret_cast<const float4*>(&h[j4 * 4]);
        s += Wd[j4 * 4 + 0] * h4.x + Wd[j4 * 4 + 1] * h4.y +
             Wd[j4 * 4 + 2] * h4.z + Wd[j4 * 4 + 3] * h4.w;
    }
    float p = (s >= 0.0f) ? s : 0.2f * s;
    pred_out[n] = p;
}

__global__ void regloss_kernel(const float* __restrict__ pred,
                               const float* __restrict__ ret,
                               const int* __restrict__ mask,
                               float* __restrict__ accums) {
    int n = blockIdx.x * blockDim.x + threadIdx.x;
    float m = (mask[n] != 0) ? 1.0f : 0.0f;
    float d = pred[n] - ret[n];
    float v = d * d * m;
#pragma unroll
    for (int off = 32; off > 0; off >>= 1) {
        v += __shfl_down(v, off, 64);
        m += __shfl_down(m, off, 64);
    }
    if ((threadIdx.x & 63) == 0) {
        atomicAdd(&accums[0], v);
        atomicAdd(&accums[1], m);
    }
}

// rank loss: 256 blocks x 16 i's each, 16-way j split per i; data staged in LDS
__global__ __launch_bounds__(256)
void rankloss_kernel(const float* __restrict__ pred,
                     const float* __restrict__ ret,
                     const int* __restrict__ mask,
                     float* __restrict__ accums) {
    __shared__ float sp[NSEQ];
    __shared__ float sg[NSEQ];
    __shared__ float sq[NSEQ];
    int tid = threadIdx.x;
    for (int idx = tid; idx < NSEQ; idx += 256) {
        sp[idx] = pred[idx];
        sg[idx] = ret[idx];
        sq[idx] = (mask[idx] != 0) ? 1.0f : 0.0f;
    }
    __syncthreads();

    int iloc = tid >> 4;       // 0..15
    int jp   = tid & 15;
    int i    = blockIdx.x * 16 + iloc;
    float pi = sp[i], gi = sg[i], qi = sq[i];
    float sum = 0.0f;
    for (int j = jp; j < NSEQ; j += 16) {
        float t = -(sp[j] - pi) * (sg[j] - gi);
        sum += fmaxf(t, 0.0f) * sq[j];
    }
    sum *= qi;
#pragma unroll
    for (int off = 32; off > 0; off >>= 1) sum += __shfl_down(sum, off, 64);
    __shared__ float wsum[4];
    if ((tid & 63) == 0) wsum[tid >> 6] = sum;
    __syncthreads();
    if (tid == 0) atomicAdd(&accums[2], wsum[0] + wsum[1] + wsum[2] + wsum[3]);
}

__global__ void final_kernel(const float* __restrict__ accums,
                             float* __restrict__ out) {
    float reg  = accums[0] / (accums[1] + 1e-8f);
    float rank = accums[2] / 16777216.0f;   // N*N
    out[NSEQ + 0] = reg + rank;
    out[NSEQ + 1] = reg;
    out[NSEQ + 2] = rank;
}

extern "C" void kernel_launch(void* const* d_in, const int* in_sizes, int n_in,
                              void* d_out, int out_size, void* d_ws, size_t ws_size,
                              hipStream_t stream) {
    const float* feat = (const float*)d_in[0];
    const float* ret  = (const float*)d_in[1];
    const int*   mask = (const int*)d_in[2];
    const float* Wih  = (const float*)d_in[3];
    const float* Whh  = (const float*)d_in[4];
    const float* bih  = (const float*)d_in[5];
    const float* bhh  = (const float*)d_in[6];
    const float* Wd   = (const float*)d_in[7];
    const float* bd   = (const float*)d_in[8];
    float* out    = (float*)d_out;
    float* accums = (float*)d_ws;            // [0..3] loss partials
    float* h_out  = (float*)d_ws + 16;       // [NSEQ][HID]

    lstm_kernel<<<NSEQ / SPB, BLK, 0, stream>>>(feat, Wih, Whh, bih, bhh, h_out);
    pred_kernel<<<NSEQ / 256, 256, 0, stream>>>(h_out, Wd, bd, out, accums);
    regloss_kernel<<<NSEQ / 256, 256, 0, stream>>>(out, ret, mask, accums);
    rankloss_kernel<<<256, 256, 0, stream>>>(out, ret, mask, accums);
    final_kernel<<<1, 1, 0, stream>>>(accums, out);
}

// Round 6
// 399.866 us; speedup vs baseline: 79.7445x; 1.3293x over previous
//
#include <hip/hip_runtime.h>

#define NSEQ   4096
#define TSTEPS 512
#define FIN    5
#define HID    64
#define SPB    16     // sequences per block (MFMA M)
#define BLK    256

// Neutral names — do NOT reuse HIP vector-type names like short8 (R4 crash)
typedef __attribute__((ext_vector_type(8))) short bsh8;    // 8 bf16 in 4 VGPRs
typedef __attribute__((ext_vector_type(4))) float f32x4;   // MFMA accumulator

#define MFMA16(A, B, C) __builtin_amdgcn_mfma_f32_16x16x32_bf16((A), (B), (C), 0, 0, 0)

struct Frag2 { bsh8 hi; bsh8 lo; };

__device__ __forceinline__ unsigned short bf16hi_rn(float x) {
    unsigned u = __float_as_uint(x);
    return (unsigned short)((u + 0x7fffu + ((u >> 16) & 1u)) >> 16);
}
__device__ __forceinline__ void split_bf16(float v, unsigned short& h, unsigned short& l) {
    h = bf16hi_rn(v);
    float hf = __uint_as_float(((unsigned)h) << 16);
    l = bf16hi_rn(v - hf);
}

__device__ __forceinline__ float fast_sigmoid(float x) {
    return __builtin_amdgcn_rcpf(1.0f + __expf(-x));
}
__device__ __forceinline__ float fast_tanh(float x) {
    return 1.0f - 2.0f * __builtin_amdgcn_rcpf(1.0f + __expf(2.0f * x));
}

// B-fragment (weights kept SPLIT hi/lo — systematic weight error stays ~2^-17)
__device__ __forceinline__ Frag2 load_whh_frag(const float* __restrict__ Whh, int gate, int k) {
    const float* p = Whh + gate * HID + k;
    Frag2 r;
#pragma unroll
    for (int j = 0; j < 8; ++j) {
        unsigned short h, l;
        split_bf16(p[j], h, l);
        r.hi[j] = (short)h; r.lo[j] = (short)l;
    }
    return r;
}
__device__ __forceinline__ Frag2 load_wih_frag(const float* __restrict__ Wih, int gate, int quad) {
    Frag2 r;
#pragma unroll
    for (int j = 0; j < 8; ++j) { r.hi[j] = 0; r.lo[j] = 0; }
    if (quad == 0) {
#pragma unroll
        for (int j = 0; j < FIN; ++j) {
            unsigned short h, l;
            split_bf16(Wih[gate * FIN + j], h, l);
            r.hi[j] = (short)h; r.lo[j] = (short)l;
        }
    }
    return r;
}

// stage one 64-step x chunk (bf16-hi only) into dst[64][SPB]
__device__ __forceinline__ void stage_chunk(const float* __restrict__ feat,
                                            bsh8 (*dst)[SPB],
                                            int seq0, int t0, int tid) {
#pragma unroll
    for (int it = 0; it < (64 * SPB) / BLK; ++it) {
        int idx = tid + it * BLK;
        int t2  = idx >> 4;
        int s   = idx & 15;
        const float* xp = feat + (size_t)(seq0 + s) * (TSTEPS * FIN) + (t0 + t2) * FIN;
        bsh8 v = {0, 0, 0, 0, 0, 0, 0, 0};
#pragma unroll
        for (int j = 0; j < FIN; ++j) v[j] = (short)bf16hi_rn(xp[j]);
        dst[t2][s] = v;
    }
}

// MFMA LSTM, A in plain bf16 (R6: dropped A.lo passes — noise-like h/x
// quantization, damped by forget gates), weights split hi/lo.
// 24 MFMA/step: 16 h-MFMAs post-barrier (critical path), 8 x-MFMAs for step
// t+1 pre-barrier (x independent of h; acc seeded with bias).
// One barrier per step. Fused pred head in the tail.
__global__ __launch_bounds__(BLK)
void lstm_kernel(const float* __restrict__ feat,
                 const float* __restrict__ Wih,
                 const float* __restrict__ Whh,
                 const float* __restrict__ bih,
                 const float* __restrict__ bhh,
                 const float* __restrict__ Wd,
                 const float* __restrict__ bd,
                 float* __restrict__ pred,
                 float* __restrict__ accums) {
    __shared__ bsh8  aA[2][SPB][9];     // h bf16-hi, double-buffered; pitch 9 vecs
    __shared__ bsh8  xb[2][64][SPB];    // x bf16-hi, chunk double buffer (32 KB)
    __shared__ float hf[SPB][HID + 1];  // final h fp32 for pred tail
    __shared__ float pf[SPB][17];       // pred partials

    const int tid  = threadIdx.x;
    const int w    = tid >> 6;
    const int lane = tid & 63;
    const int col  = lane & 15;         // MFMA col / A-row (seq)
    const int quad = lane >> 4;
    const int u    = 16 * w + col;      // unit handled by this lane
    const int seq0 = blockIdx.x * SPB;

    if (blockIdx.x == 0 && tid < 4) accums[tid] = 0.0f;   // loss accumulators

    // ---- persistent B fragments (named structs — R1/R2 spill lessons) ----
    const int g0 = 0 * HID + u, g1 = 1 * HID + u, g2 = 2 * HID + u, g3 = 3 * HID + u;
    Frag2 b00 = load_whh_frag(Whh, g0, quad * 8);
    Frag2 b01 = load_whh_frag(Whh, g0, 32 + quad * 8);
    Frag2 b02 = load_wih_frag(Wih, g0, quad);
    Frag2 b10 = load_whh_frag(Whh, g1, quad * 8);
    Frag2 b11 = load_whh_frag(Whh, g1, 32 + quad * 8);
    Frag2 b12 = load_wih_frag(Wih, g1, quad);
    Frag2 b20 = load_whh_frag(Whh, g2, quad * 8);
    Frag2 b21 = load_whh_frag(Whh, g2, 32 + quad * 8);
    Frag2 b22 = load_wih_frag(Wih, g2, quad);
    Frag2 b30 = load_whh_frag(Whh, g3, quad * 8);
    Frag2 b31 = load_whh_frag(Whh, g3, 32 + quad * 8);
    Frag2 b32 = load_wih_frag(Wih, g3, quad);

    const float bi  = bih[g0] + bhh[g0];
    const float bf_ = bih[g1] + bhh[g1];
    const float bg  = bih[g2] + bhh[g2];
    const float bo  = bih[g3] + bhh[g3];

    // zero h buffer 0 (144 vectors)
    {
        bsh8 z = {0, 0, 0, 0, 0, 0, 0, 0};
        if (tid < SPB * 9) (&aA[0][0][0])[tid] = z;
    }
    stage_chunk(feat, xb[0], seq0, 0, tid);
    __syncthreads();

    // acc := bias + x-part of step 0 (8 MFMAs)
    f32x4 acc0 = {bi,  bi,  bi,  bi };
    f32x4 acc1 = {bf_, bf_, bf_, bf_};
    f32x4 acc2 = {bg,  bg,  bg,  bg };
    f32x4 acc3 = {bo,  bo,  bo,  bo };
    {
        bsh8 ax = xb[0][0][col];
        acc0 = MFMA16(ax, b02.hi, acc0); acc0 = MFMA16(ax, b02.lo, acc0);
        acc1 = MFMA16(ax, b12.hi, acc1); acc1 = MFMA16(ax, b12.lo, acc1);
        acc2 = MFMA16(ax, b22.hi, acc2); acc2 = MFMA16(ax, b22.lo, acc2);
        acc3 = MFMA16(ax, b32.hi, acc3); acc3 = MFMA16(ax, b32.lo, acc3);
    }

    float c_[4] = {0.f, 0.f, 0.f, 0.f};

    for (int t = 0; t < TSTEPS; ++t) {
        const int tt  = t & 63;
        const int buf = t & 1;
        const int nb  = buf ^ 1;
        __syncthreads();   // h(t-1) writes + staged x visible

        // prefetch-stage next chunk (its buffer had 2+ barriers since last read)
        if (tt == 0 && t + 64 < TSTEPS) {
            int nc = (t >> 6) + 1;
            stage_chunk(feat, xb[nc & 1], seq0, nc * 64, tid);
        }

        // ---- 16 h-MFMAs (critical path) ----
        bsh8 ah0 = aA[buf][col][quad];
        bsh8 ah1 = aA[buf][col][4 + quad];
        acc0 = MFMA16(ah0, b00.hi, acc0); acc0 = MFMA16(ah1, b01.hi, acc0);
        acc1 = MFMA16(ah0, b10.hi, acc1); acc1 = MFMA16(ah1, b11.hi, acc1);
        acc2 = MFMA16(ah0, b20.hi, acc2); acc2 = MFMA16(ah1, b21.hi, acc2);
        acc3 = MFMA16(ah0, b30.hi, acc3); acc3 = MFMA16(ah1, b31.hi, acc3);
        acc0 = MFMA16(ah0, b00.lo, acc0); acc0 = MFMA16(ah1, b01.lo, acc0);
        acc1 = MFMA16(ah0, b10.lo, acc1); acc1 = MFMA16(ah1, b11.lo, acc1);
        acc2 = MFMA16(ah0, b20.lo, acc2); acc2 = MFMA16(ah1, b21.lo, acc2);
        acc3 = MFMA16(ah0, b30.lo, acc3); acc3 = MFMA16(ah1, b31.lo, acc3);

        // ---- epilogue: C/D layout col=lane&15 (unit), row=quad*4+r (seq) ----
#pragma unroll
        for (int r = 0; r < 4; ++r) {
            float gi = fast_sigmoid(acc0[r]);
            float gf = fast_sigmoid(acc1[r]);
            float gg = fast_tanh  (acc2[r]);
            float go = fast_sigmoid(acc3[r]);
            c_[r] = gf * c_[r] + gi * gg;
            float hh = go * fast_tanh(c_[r]);
            int seqr = quad * 4 + r;
            ((unsigned short*)&aA[nb][seqr][0])[u] = bf16hi_rn(hh);
            if (t == TSTEPS - 1) hf[seqr][u] = hh;
        }

        // ---- x-part of step t+1 (off critical path; before next barrier) ----
        if (t < TSTEPS - 1) {
            int t1 = t + 1;
            bsh8 ax = xb[(t1 >> 6) & 1][t1 & 63][col];
            acc0 = (f32x4){bi,  bi,  bi,  bi };
            acc1 = (f32x4){bf_, bf_, bf_, bf_};
            acc2 = (f32x4){bg,  bg,  bg,  bg };
            acc3 = (f32x4){bo,  bo,  bo,  bo };
            acc0 = MFMA16(ax, b02.hi, acc0); acc0 = MFMA16(ax, b02.lo, acc0);
            acc1 = MFMA16(ax, b12.hi, acc1); acc1 = MFMA16(ax, b12.lo, acc1);
            acc2 = MFMA16(ax, b22.hi, acc2); acc2 = MFMA16(ax, b22.lo, acc2);
            acc3 = MFMA16(ax, b32.hi, acc3); acc3 = MFMA16(ax, b32.lo, acc3);
        }
    }
    __syncthreads();   // hf visible

    // ---- fused pred head: pred = leaky_relu(h @ Wd^T + bd) ----
    {
        int s  = tid & 15;
        int q4 = tid >> 4;           // 16 unit-groups of 4
        int j0 = q4 * 4;
        float part = hf[s][j0] * Wd[j0] + hf[s][j0 + 1] * Wd[j0 + 1]
                   + hf[s][j0 + 2] * Wd[j0 + 2] + hf[s][j0 + 3] * Wd[j0 + 3];
        pf[s][q4] = part;
    }
    __syncthreads();
    if (tid < SPB) {
        float sum = bd[0];
#pragma unroll
        for (int j = 0; j < 16; ++j) sum += pf[tid][j];
        float p = (sum >= 0.0f) ? sum : 0.2f * sum;
        pred[seq0 + tid] = p;
    }
}

// fused losses: every block does a 16-i rank slice; block 0 also does reg MSE
__global__ __launch_bounds__(256)
void loss_kernel(const float* __restrict__ pred,
                 const float* __restrict__ ret,
                 const int* __restrict__ mask,
                 float* __restrict__ accums) {
    __shared__ float sp[NSEQ];
    __shared__ float sg[NSEQ];
    __shared__ float sq[NSEQ];
    int tid = threadIdx.x;
    for (int idx = tid; idx < NSEQ; idx += 256) {
        sp[idx] = pred[idx];
        sg[idx] = ret[idx];
        sq[idx] = (mask[idx] != 0) ? 1.0f : 0.0f;
    }
    __syncthreads();

    if (blockIdx.x == 0) {   // regression loss partials
        float v = 0.0f, m = 0.0f;
        for (int j = tid; j < NSEQ; j += 256) {
            float mj = sq[j];
            float d  = sp[j] - sg[j];
            v += d * d * mj;
            m += mj;
        }
#pragma unroll
        for (int off = 32; off > 0; off >>= 1) {
            v += __shfl_down(v, off, 64);
            m += __shfl_down(m, off, 64);
        }
        if ((tid & 63) == 0) {
            atomicAdd(&accums[0], v);
            atomicAdd(&accums[1], m);
        }
    }

    int iloc = tid >> 4;
    int jp   = tid & 15;
    int i    = blockIdx.x * 16 + iloc;
    float pi = sp[i], gi = sg[i], qi = sq[i];
    float sum = 0.0f;
    for (int j = jp; j < NSEQ; j += 16) {
        float t = -(sp[j] - pi) * (sg[j] - gi);
        sum += fmaxf(t, 0.0f) * sq[j];
    }
    sum *= qi;
#pragma unroll
    for (int off = 32; off > 0; off >>= 1) sum += __shfl_down(sum, off, 64);
    __shared__ float wsum[4];
    if ((tid & 63) == 0) wsum[tid >> 6] = sum;
    __syncthreads();
    if (tid == 0) atomicAdd(&accums[2], wsum[0] + wsum[1] + wsum[2] + wsum[3]);
}

__global__ void final_kernel(const float* __restrict__ accums,
                             float* __restrict__ out) {
    float reg  = accums[0] / (accums[1] + 1e-8f);
    float rank = accums[2] / 16777216.0f;   // N*N
    out[NSEQ + 0] = reg + rank;
    out[NSEQ + 1] = reg;
    out[NSEQ + 2] = rank;
}

extern "C" void kernel_launch(void* const* d_in, const int* in_sizes, int n_in,
                              void* d_out, int out_size, void* d_ws, size_t ws_size,
                              hipStream_t stream) {
    const float* feat = (const float*)d_in[0];
    const float* ret  = (const float*)d_in[1];
    const int*   mask = (const int*)d_in[2];
    const float* Wih  = (const float*)d_in[3];
    const float* Whh  = (const float*)d_in[4];
    const float* bih  = (const float*)d_in[5];
    const float* bhh  = (const float*)d_in[6];
    const float* Wd   = (const float*)d_in[7];
    const float* bd   = (const float*)d_in[8];
    float* out    = (float*)d_out;
    float* accums = (float*)d_ws;            // [0..3] loss partials

    lstm_kernel<<<NSEQ / SPB, BLK, 0, stream>>>(feat, Wih, Whh, bih, bhh,
                                                Wd, bd, out, accums);
    loss_kernel<<<NSEQ / 16, 256, 0, stream>>>(out, ret, mask, accums);
    final_kernel<<<1, 1, 0, stream>>>(accums, out);
}